// Round 2
// baseline (1282.022 us; speedup 1.0000x reference)
//
#include <hip/hip_runtime.h>

#define Gn 128
#define Tn 512
#define Sn 24
#define SP 28   // padded LDS row stride (16B-aligned, avoids 6-way bank aliasing of stride 24)
#define Mn 4
#define COVS_BASE (Gn * Tn * Mn)   // 262144

__device__ __forceinline__ float4 ld4(const float* p) {
    return *reinterpret_cast<const float4*>(p);
}
__device__ __forceinline__ void st4(float* p, float4 v) {
    *reinterpret_cast<float4*>(p) = v;
}
__device__ __forceinline__ float dot4(float4 a, float4 b) {
    return a.x*b.x + a.y*b.y + a.z*b.z + a.w*b.w;
}

struct Row24 { float4 v[6]; };

__device__ __forceinline__ Row24 loadRow(const float* p) {
    Row24 r;
#pragma unroll
    for (int i = 0; i < 6; ++i) r.v[i] = ld4(p + 4*i);
    return r;
}

__device__ __forceinline__ float dot24(const Row24& a, const float* b) {
    float4 b0 = ld4(b+0), b1 = ld4(b+4), b2 = ld4(b+8),
           b3 = ld4(b+12), b4 = ld4(b+16), b5 = ld4(b+20);
    float s0 = a.v[0].x*b0.x + a.v[0].y*b0.y + a.v[0].z*b0.z + a.v[0].w*b0.w;
    float s1 = a.v[1].x*b1.x + a.v[1].y*b1.y + a.v[1].z*b1.z + a.v[1].w*b1.w;
    float s2 = a.v[2].x*b2.x + a.v[2].y*b2.y + a.v[2].z*b2.z + a.v[2].w*b2.w;
    float s3 = a.v[3].x*b3.x + a.v[3].y*b3.y + a.v[3].z*b3.z + a.v[3].w*b3.w;
    float s4 = a.v[4].x*b4.x + a.v[4].y*b4.y + a.v[4].z*b4.z + a.v[4].w*b4.w;
    float s5 = a.v[5].x*b5.x + a.v[5].y*b5.y + a.v[5].z*b5.z + a.v[5].w*b5.w;
    return ((s0+s1)+(s2+s3))+(s4+s5);
}

// Raw barrier: waits only LDS (lgkmcnt), NOT vmcnt -> prefetch global loads stay
// in flight across the barrier (the __syncthreads vmcnt(0) drain would kill the
// distance-1 prefetch). asm memory clobbers pin compiler ordering.
__device__ __forceinline__ void barrierLds() {
    asm volatile("s_waitcnt lgkmcnt(0)" ::: "memory");
    __builtin_amdgcn_s_barrier();
    asm volatile("" ::: "memory");
}
// Wave-internal LDS RAW ordering (wave 0 only): lockstep HW + lgkm wait.
__device__ __forceinline__ void waveLds() {
    asm volatile("s_waitcnt lgkmcnt(0)" ::: "memory");
    __builtin_amdgcn_wave_barrier();
    asm volatile("" ::: "memory");
}

extern "C" __global__ void __launch_bounds__(256)
kalman_kernel(const float* __restrict__ y_g, const float* __restrict__ F_g,
              const float* __restrict__ Q_g, const float* __restrict__ H_g,
              const float* __restrict__ R_g, const float* __restrict__ m0_g,
              const float* __restrict__ P0_g, float* __restrict__ out)
{
    const int g   = blockIdx.x;
    const int tid = threadIdx.x;
    const int gT  = g * Tn;

    __shared__ __align__(16) float sP[Sn*SP];      // covariance (symmetric)
    __shared__ __align__(16) float sPu[Sn*SP];     // updated covariance
    __shared__ __align__(16) float sTmp[Sn*SP];    // F @ Pu
    __shared__ __align__(16) float sF[2][Sn*SP];
    __shared__ __align__(16) float sQ[2][Sn*SP];
    __shared__ __align__(16) float sH[2][Mn*SP];
    __shared__ __align__(16) float sR[2][16];
    __shared__ __align__(16) float sy[2][4];
    __shared__ __align__(16) float sHP[Mn*SP];     // H@P rows
    __shared__ __align__(16) float sHPT[Sn*4];     // (H@P)^T rows (4 wide)
    __shared__ __align__(16) float sK[Sn*4];       // Kalman gain rows (4 wide)
    __shared__ __align__(16) float sSig[16];
    __shared__ __align__(16) float sInv[16];
    __shared__ __align__(16) float sMean[Sn];
    __shared__ __align__(16) float sMu_[Sn];       // m_u
    __shared__ __align__(16) float sResid[4];

    const float4* F4 = reinterpret_cast<const float4*>(F_g);
    const float4* Q4 = reinterpret_cast<const float4*>(Q_g);
    const float4* H4 = reinterpret_cast<const float4*>(H_g);
    const float4* R4 = reinterpret_cast<const float4*>(R_g);
    const float4* y4 = reinterpret_cast<const float4*>(y_g);

    // stage mapping: 317 float4 per step: F 144, Q 144, H 24, R 4, y 1
    auto stage_load = [&](int v, int t) -> float4 {
        if (v < 144)      return F4[(gT + t)*144 + v];
        else if (v < 288) return Q4[(gT + t)*144 + (v-144)];
        else if (v < 312) return H4[(gT + t)*24  + (v-288)];
        else if (v < 316) return R4[(gT + t)*4   + (v-312)];
        else              return y4[gT + t];
    };
    auto stage_store = [&](int v, int bb, float4 val) {
        if (v < 144)      { int r = v/6,        c = (v%6)*4;       st4(&sF[bb][r*SP+c], val); }
        else if (v < 288) { int v2 = v-144; int r = v2/6, c = (v2%6)*4; st4(&sQ[bb][r*SP+c], val); }
        else if (v < 312) { int v2 = v-288; int r = v2/6, c = (v2%6)*4; st4(&sH[bb][r*SP+c], val); }
        else if (v < 316) { st4(&sR[bb][(v-312)*4], val); }
        else              { st4(&sy[bb][0], val); }
    };

    // ---------------- prologue ----------------
    if (tid < 144) {
        int r = tid / 6, c = (tid % 6) * 4;
        st4(&sP[r*SP + c], ld4(&P0_g[g*Sn*Sn + tid*4]));
    } else if (tid < 150) {
        int v = tid - 144;
        st4(&sMean[v*4], ld4(&m0_g[g*Sn + v*4]));
    }
    {   // stage t=0 synchronously
        float4 a0 = stage_load(tid, 0);
        stage_store(tid, 0, a0);
        if (tid + 256 < 317) {
            float4 a1 = stage_load(tid + 256, 0);
            stage_store(tid + 256, 0, a1);
        }
    }
    barrierLds();

    float4 pf0, pf1;

    for (int t = 0; t < Tn; ++t) {
        const int  b    = t & 1;
        const int  b1   = b ^ 1;
        const bool last = (t == Tn - 1);

        // ---- Phase A: prefetch-issue(t+1); HP = H@P; mu, resid ----
        if (!last) {
            pf0 = stage_load(tid, t+1);
            if (tid + 256 < 317) pf1 = stage_load(tid + 256, t+1);
        }
        if (tid < 96) {
            int a = tid / 24, s = tid % 24;
            Row24 hr = loadRow(&sH[b][a*SP]);
            float hp = dot24(hr, &sP[s*SP]);     // P symmetric: col s == row s
            sHP[a*SP + s]  = hp;
            sHPT[s*4 + a]  = hp;
        } else if (tid >= 128 && tid < 132) {
            int a = tid - 128;
            Row24 hr = loadRow(&sH[b][a*SP]);
            float mu = dot24(hr, sMean);
            out[(gT + t)*4 + a] = mu;            // means output
            sResid[a] = sy[b][a] - mu;
        }
        barrierLds();

        // ---- Phase B/C/D (wave 0, wave-synchronous): Sig -> Inv -> K ----
        if (tid < 64) {
            if (tid < 16) {
                int a = tid >> 2, c = tid & 3;
                Row24 hpr = loadRow(&sHP[a*SP]);
                float sig = dot24(hpr, &sH[b][c*SP]) + sR[b][tid];
                sSig[tid] = sig;
                out[COVS_BASE + (size_t)(gT + t)*16 + tid] = sig;  // covs output
            }
            if (!last) {
                waveLds();
                if (tid < 16) {
                    float s00=sSig[0],  s01=sSig[1],  s02=sSig[2],  s03=sSig[3];
                    float s10=sSig[4],  s11=sSig[5],  s12=sSig[6],  s13=sSig[7];
                    float s20=sSig[8],  s21=sSig[9],  s22=sSig[10], s23=sSig[11];
                    float s30=sSig[12], s31=sSig[13], s32=sSig[14], s33=sSig[15];
                    float p0 = s00*s11 - s01*s10;
                    float p1 = s00*s12 - s02*s10;
                    float p2 = s00*s13 - s03*s10;
                    float p3 = s01*s12 - s02*s11;
                    float p4 = s01*s13 - s03*s11;
                    float p5 = s02*s13 - s03*s12;
                    float q0c = s20*s31 - s21*s30;
                    float q1c = s20*s32 - s22*s30;
                    float q2c = s20*s33 - s23*s30;
                    float q3c = s21*s32 - s22*s31;
                    float q4c = s21*s33 - s23*s31;
                    float q5c = s22*s33 - s23*s32;
                    float det  = p0*q5c - p1*q4c + p2*q3c + p3*q2c - p4*q1c + p5*q0c;
                    float rdet = 1.0f / det;
                    int ia = tid >> 2, ic = tid & 3;   // Inv[ia][ic] = cof(ic,ia)/det
                    int r0 = (ic==0)?1:0, r1 = (ic<=1)?2:1, r2 = (ic<=2)?3:2;
                    int u0 = (ia==0)?1:0, u1 = (ia<=1)?2:1, u2 = (ia<=2)?3:2;
                    float m00=sSig[r0*4+u0], m01=sSig[r0*4+u1], m02=sSig[r0*4+u2];
                    float m10=sSig[r1*4+u0], m11=sSig[r1*4+u1], m12=sSig[r1*4+u2];
                    float m20=sSig[r2*4+u0], m21=sSig[r2*4+u1], m22=sSig[r2*4+u2];
                    float minor = m00*(m11*m22 - m12*m21)
                                - m01*(m10*m22 - m12*m20)
                                + m02*(m10*m21 - m11*m20);
                    float cof = ((ia + ic) & 1) ? -minor : minor;
                    sInv[tid] = cof * rdet;
                }
                waveLds();
                {   // K^T = Inv @ HP  (96 outs over 64 lanes); store as K[s][a]
                    int a = tid / 24, s = tid % 24;
                    float kt = dot4(ld4(&sInv[a*4]), ld4(&sHPT[s*4]));
                    sK[s*4 + a] = kt;
                    if (tid < 32) {
                        int o2 = 64 + tid, a3 = o2/24, s3 = o2%24;
                        float kt2 = dot4(ld4(&sInv[a3*4]), ld4(&sHPT[s3*4]));
                        sK[s3*4 + a3] = kt2;
                    }
                }
            }
        }
        if (last) return;
        barrierLds();

        // ---- Phase E: Pu = P - K@HP (pair map) ; m_u ----
        {
            int o = 2*tid, i = o/24, j = o%24;
            float4 kr = ld4(&sK[i*4]);
            float pu0 = sP[i*SP+j]   - dot4(kr, ld4(&sHPT[j*4]));
            float pu1 = sP[i*SP+j+1] - dot4(kr, ld4(&sHPT[(j+1)*4]));
            sPu[i*SP+j]   = pu0;
            sPu[i*SP+j+1] = pu1;
            if (tid >= 64 && tid < 128) {   // tail outs 512..575 on wave 1
                int o2 = 512 + (tid-64), i2 = o2/24, j2 = o2%24;
                sPu[i2*SP+j2] = sP[i2*SP+j2] - dot4(ld4(&sK[i2*4]), ld4(&sHPT[j2*4]));
            }
            if (tid >= 192 && tid < 216) {  // m_u on wave 3
                int s = tid - 192;
                sMu_[s] = sMean[s] + dot4(ld4(&sK[s*4]), ld4(&sResid[0]));
            }
        }
        barrierLds();

        // ---- Phase F: Tmp = F @ Pu (Pu symmetric -> row·row) ; m = F @ m_u ----
        {
            int o = 2*tid, i = o/24, j = o%24;
            Row24 fr = loadRow(&sF[b][i*SP]);
            sTmp[i*SP+j]   = dot24(fr, &sPu[j*SP]);
            sTmp[i*SP+j+1] = dot24(fr, &sPu[(j+1)*SP]);
            if (tid >= 64 && tid < 128) {
                int o2 = 512 + (tid-64), i2 = o2/24, j2 = o2%24;
                Row24 fr2 = loadRow(&sF[b][i2*SP]);
                sTmp[i2*SP+j2] = dot24(fr2, &sPu[j2*SP]);
            }
            if (tid >= 224 && tid < 248) {
                int i3 = tid - 224;
                Row24 fr3 = loadRow(&sF[b][i3*SP]);
                sMean[i3] = dot24(fr3, sMu_);
            }
        }
        barrierLds();

        // ---- Phase G: P = Tmp @ F^T + Q ; store prefetched staging ----
        {
            int o = 2*tid, i = o/24, j = o%24;
            Row24 tr = loadRow(&sTmp[i*SP]);
            sP[i*SP+j]   = dot24(tr, &sF[b][j*SP])     + sQ[b][i*SP+j];
            sP[i*SP+j+1] = dot24(tr, &sF[b][(j+1)*SP]) + sQ[b][i*SP+j+1];
            if (tid >= 64 && tid < 128) {
                int o2 = 512 + (tid-64), i2 = o2/24, j2 = o2%24;
                Row24 tr2 = loadRow(&sTmp[i2*SP]);
                sP[i2*SP+j2] = dot24(tr2, &sF[b][j2*SP]) + sQ[b][i2*SP+j2];
            }
            // land the t+1 prefetch into the other staging buffer
            stage_store(tid, b1, pf0);
            if (tid + 256 < 317) stage_store(tid + 256, b1, pf1);
        }
        barrierLds();
    }
}

extern "C" void kernel_launch(void* const* d_in, const int* in_sizes, int n_in,
                              void* d_out, int out_size, void* d_ws, size_t ws_size,
                              hipStream_t stream) {
    kalman_kernel<<<Gn, 256, 0, stream>>>(
        (const float*)d_in[0], (const float*)d_in[1], (const float*)d_in[2],
        (const float*)d_in[3], (const float*)d_in[4], (const float*)d_in[5],
        (const float*)d_in[6], (float*)d_out);
}